// Round 1
// baseline (442.298 us; speedup 1.0000x reference)
//
#include <hip/hip_runtime.h>
#include <hip/hip_bf16.h>

// GCN: N=20000 nodes, F_IN=512, H=256, C=40, E=640000 edges, fp32.
// out = A_norm @ relu(A_norm @ (x@W1) + b1) @ W2-form, where A_norm includes
// self loops with dinv = rsqrt(in_deg+1), edge coef dinv[src]*dinv[dst],
// self coef dinv[i]^2. TEMPERATURE = 1.0 (no-op).

#define N_NODES 20000
#define F_IN    512
#define H_DIM   256
#define C_DIM   40
#define E_EDGES 640000

// ---------------- degree / CSR build ----------------

__global__ void count_kernel(const int* __restrict__ dst, int* __restrict__ cnt) {
    int e = blockIdx.x * blockDim.x + threadIdx.x;
    if (e < E_EDGES) atomicAdd(&cnt[dst[e]], 1);
}

__global__ void dinv_kernel(const int* __restrict__ cnt, float* __restrict__ dinv) {
    int i = blockIdx.x * blockDim.x + threadIdx.x;
    if (i < N_NODES) dinv[i] = rsqrtf((float)cnt[i] + 1.0f);
}

// single-block exclusive scan of cnt[N] -> rowptr[N+1]
__global__ void scan_kernel(const int* __restrict__ cnt, int* __restrict__ rowptr) {
    __shared__ int sums[256];
    const int t = threadIdx.x;
    const int CH = (N_NODES + 255) / 256;   // 79
    int begin = t * CH;
    int end = begin + CH; if (end > N_NODES) end = N_NODES;
    int s = 0;
    for (int i = begin; i < end; ++i) s += cnt[i];
    sums[t] = s;
    __syncthreads();
    if (t == 0) {
        int run = 0;
        for (int i = 0; i < 256; ++i) { int v = sums[i]; sums[i] = run; run += v; }
    }
    __syncthreads();
    int run = sums[t];
    for (int i = begin; i < end; ++i) { rowptr[i] = run; run += cnt[i]; }
    if (t == 0) rowptr[N_NODES] = E_EDGES;
}

__global__ void fill_kernel(const int* __restrict__ src, const int* __restrict__ dst,
                            const int* __restrict__ rowptr, int* __restrict__ cursor,
                            int* __restrict__ esrc) {
    int e = blockIdx.x * blockDim.x + threadIdx.x;
    if (e < E_EDGES) {
        int d = dst[e];
        int pos = atomicAdd(&cursor[d], 1);
        esrc[rowptr[d] + pos] = src[e];
    }
}

// ---------------- GEMM1: h1[M,256] = x[M,512] @ W1[512,256] (fp32 tiled) ----------------

__global__ __launch_bounds__(256) void gemm1_kernel(const float* __restrict__ A,
                                                    const float* __restrict__ B,
                                                    float* __restrict__ C) {
    __shared__ float As[16][64];   // transposed A tile: As[k][m]
    __shared__ float Bs[16][64];   // Bs[k][n]
    const int tid = threadIdx.x;
    const int row0 = blockIdx.y * 64;
    const int col0 = blockIdx.x * 64;
    const int tx = tid & 15, ty = tid >> 4;
    const int ar = tid >> 2;          // 0..63 tile row
    const int ak = (tid & 3) << 2;    // 0,4,8,12
    const int bk = tid >> 4;          // 0..15
    const int bc = (tid & 15) << 2;   // 0..60
    float acc[4][4] = {};
    for (int k0 = 0; k0 < F_IN; k0 += 16) {
        float4 a4 = make_float4(0.f, 0.f, 0.f, 0.f);
        int gr = row0 + ar;
        if (gr < N_NODES) a4 = *(const float4*)&A[(size_t)gr * F_IN + k0 + ak];
        As[ak + 0][ar] = a4.x; As[ak + 1][ar] = a4.y;
        As[ak + 2][ar] = a4.z; As[ak + 3][ar] = a4.w;
        float4 b4 = *(const float4*)&B[(size_t)(k0 + bk) * H_DIM + col0 + bc];
        *(float4*)&Bs[bk][bc] = b4;
        __syncthreads();
#pragma unroll
        for (int kk = 0; kk < 16; ++kk) {
            float4 a = *(const float4*)&As[kk][ty << 2];
            float4 b = *(const float4*)&Bs[kk][tx << 2];
            acc[0][0] = fmaf(a.x, b.x, acc[0][0]); acc[0][1] = fmaf(a.x, b.y, acc[0][1]);
            acc[0][2] = fmaf(a.x, b.z, acc[0][2]); acc[0][3] = fmaf(a.x, b.w, acc[0][3]);
            acc[1][0] = fmaf(a.y, b.x, acc[1][0]); acc[1][1] = fmaf(a.y, b.y, acc[1][1]);
            acc[1][2] = fmaf(a.y, b.z, acc[1][2]); acc[1][3] = fmaf(a.y, b.w, acc[1][3]);
            acc[2][0] = fmaf(a.z, b.x, acc[2][0]); acc[2][1] = fmaf(a.z, b.y, acc[2][1]);
            acc[2][2] = fmaf(a.z, b.z, acc[2][2]); acc[2][3] = fmaf(a.z, b.w, acc[2][3]);
            acc[3][0] = fmaf(a.w, b.x, acc[3][0]); acc[3][1] = fmaf(a.w, b.y, acc[3][1]);
            acc[3][2] = fmaf(a.w, b.z, acc[3][2]); acc[3][3] = fmaf(a.w, b.w, acc[3][3]);
        }
        __syncthreads();
    }
#pragma unroll
    for (int i = 0; i < 4; ++i) {
        int r = row0 + (ty << 2) + i;
        if (r < N_NODES)
            *(float4*)&C[(size_t)r * H_DIM + col0 + (tx << 2)] =
                make_float4(acc[i][0], acc[i][1], acc[i][2], acc[i][3]);
    }
}

// ---------------- agg1: wave per node, 256-dim gather + self + b1 + relu ----------------

__global__ __launch_bounds__(256) void agg1_kernel(const float* __restrict__ h1,
                                                   const int* __restrict__ rowptr,
                                                   const int* __restrict__ esrc,
                                                   const float* __restrict__ dinv,
                                                   const float* __restrict__ b1,
                                                   float* __restrict__ hr) {
    const int wave = (blockIdx.x * 256 + threadIdx.x) >> 6;   // node id, exactly N_NODES waves
    const int lane = threadIdx.x & 63;
    const int f0 = lane << 2;                                  // 4 features per lane
    const int i = wave;
    const float di = dinv[i];
    const int rb = rowptr[i], re = rowptr[i + 1];
    float4 sv = *(const float4*)&h1[(size_t)i * H_DIM + f0];
    const float wself = di * di;
    float4 acc = make_float4(wself * sv.x, wself * sv.y, wself * sv.z, wself * sv.w);
    for (int k = rb; k < re; ++k) {
        int s = esrc[k];
        float w = dinv[s] * di;
        float4 v = *(const float4*)&h1[(size_t)s * H_DIM + f0];
        acc.x = fmaf(w, v.x, acc.x);
        acc.y = fmaf(w, v.y, acc.y);
        acc.z = fmaf(w, v.z, acc.z);
        acc.w = fmaf(w, v.w, acc.w);
    }
    float4 bb = *(const float4*)&b1[f0];
    acc.x = fmaxf(acc.x + bb.x, 0.f);
    acc.y = fmaxf(acc.y + bb.y, 0.f);
    acc.z = fmaxf(acc.z + bb.z, 0.f);
    acc.w = fmaxf(acc.w + bb.w, 0.f);
    *(float4*)&hr[(size_t)i * H_DIM + f0] = acc;
}

// ---------------- GEMM2: h2[M,40] = hr[M,256] @ W2[256,40] ----------------

__global__ __launch_bounds__(256) void gemm2_kernel(const float* __restrict__ hr,
                                                    const float* __restrict__ W2,
                                                    float* __restrict__ h2) {
    __shared__ float w2s[H_DIM * C_DIM];   // 40 KiB
    const int tid = threadIdx.x;
#pragma unroll
    for (int i = 0; i < (H_DIM * C_DIM) / 256; ++i) w2s[i * 256 + tid] = W2[i * 256 + tid];
    __syncthreads();
    const int g = blockIdx.x * 256 + tid;          // 0..799999, exact
    const int n = g / C_DIM;
    const int c = g - n * C_DIM;
    const float* __restrict__ row = &hr[(size_t)n * H_DIM];
    float acc = 0.f;
#pragma unroll 8
    for (int k = 0; k < H_DIM; ++k) acc = fmaf(row[k], w2s[k * C_DIM + c], acc);
    h2[g] = acc;
}

// ---------------- agg2: wave per node, 40-dim gather + self + b2 ----------------

__global__ __launch_bounds__(256) void agg2_kernel(const float* __restrict__ h2,
                                                   const int* __restrict__ rowptr,
                                                   const int* __restrict__ esrc,
                                                   const float* __restrict__ dinv,
                                                   const float* __restrict__ b2,
                                                   float* __restrict__ out) {
    const int wave = (blockIdx.x * 256 + threadIdx.x) >> 6;   // node id
    const int lane = threadIdx.x & 63;
    const int cl = lane < C_DIM ? lane : C_DIM - 1;           // clamp to stay in-bounds
    const int i = wave;
    const float di = dinv[i];
    const int rb = rowptr[i], re = rowptr[i + 1];
    float acc = di * di * h2[(size_t)i * C_DIM + cl] + b2[cl];
    for (int k = rb; k < re; ++k) {
        int s = esrc[k];
        float w = dinv[s] * di;
        acc = fmaf(w, h2[(size_t)s * C_DIM + cl], acc);
    }
    if (lane < C_DIM) out[(size_t)i * C_DIM + lane] = acc;
}

// ---------------- launch ----------------

extern "C" void kernel_launch(void* const* d_in, const int* in_sizes, int n_in,
                              void* d_out, int out_size, void* d_ws, size_t ws_size,
                              hipStream_t stream) {
    const float* x   = (const float*)d_in[0];
    const int*   ei  = (const int*)d_in[1];
    const float* W1  = (const float*)d_in[2];
    const float* b1  = (const float*)d_in[3];
    const float* W2  = (const float*)d_in[4];
    const float* b2  = (const float*)d_in[5];
    float* out = (float*)d_out;

    const int* src = ei;            // edge_index[0]
    const int* dst = ei + E_EDGES;  // edge_index[1]

    // workspace layout (all offsets 16B-aligned)
    char* ws = (char*)d_ws;
    int*   cnt    = (int*)(ws + 0);             // N ints          (80000 B)
    float* dinv   = (float*)(ws + 80000);       // N floats        (80000 B)
    int*   rowptr = (int*)(ws + 160000);        // N+1 ints        (80004 B -> pad 80016)
    int*   cursor = (int*)(ws + 240016);        // N ints          (80000 B)
    int*   esrc   = (int*)(ws + 320016);        // E ints          (2560000 B)
    float* h1     = (float*)(ws + 2880016);     // N*H floats      (20480000 B)
    float* hr     = (float*)(ws + 23360016);    // N*H floats      (20480000 B)
    float* h2     = (float*)(ws + 43840016);    // N*C floats      (3200000 B)
    // total 47,040,016 B

    hipMemsetAsync(cnt, 0, N_NODES * sizeof(int), stream);
    hipMemsetAsync(cursor, 0, N_NODES * sizeof(int), stream);

    count_kernel<<<(E_EDGES + 255) / 256, 256, 0, stream>>>(dst, cnt);
    dinv_kernel<<<(N_NODES + 255) / 256, 256, 0, stream>>>(cnt, dinv);
    scan_kernel<<<1, 256, 0, stream>>>(cnt, rowptr);
    fill_kernel<<<(E_EDGES + 255) / 256, 256, 0, stream>>>(src, dst, rowptr, cursor, esrc);

    dim3 g1(H_DIM / 64, (N_NODES + 63) / 64);   // 4 x 313
    gemm1_kernel<<<g1, 256, 0, stream>>>(x, W1, h1);

    agg1_kernel<<<N_NODES / 4, 256, 0, stream>>>(h1, rowptr, esrc, dinv, b1, hr);

    gemm2_kernel<<<(N_NODES * C_DIM) / 256, 256, 0, stream>>>(hr, W2, h2);

    agg2_kernel<<<N_NODES / 4, 256, 0, stream>>>(h2, rowptr, esrc, dinv, b2, out);
}

// Round 2
// 329.768 us; speedup vs baseline: 1.3412x; 1.3412x over previous
//
#include <hip/hip_runtime.h>
#include <hip/hip_bf16.h>

// GCN 2-layer, N=20000, F_IN=512, H=256, C=40, E=640000, fp32 in/out.
// Dataflow: CSR build -> gemm1 (bf16 MFMA, x@W1 -> h1b bf16)
//        -> agg1 (gather h1b, +b1, relu -> hrb bf16)
//        -> gemm2 (bf16 MFMA, hrb@W2 -> h2b bf16, N padded to 64)
//        -> agg2 (gather h2b, +b2 -> out fp32)

#define N_NODES 20000
#define F_IN    512
#define H_DIM   256
#define C_DIM   40
#define C_PAD   64
#define E_EDGES 640000

typedef __attribute__((ext_vector_type(8))) short short8;
typedef __attribute__((ext_vector_type(4))) float floatx4;

__device__ __forceinline__ float bf2f(unsigned short u) {
    union { unsigned int i; float f; } v;
    v.i = ((unsigned int)u) << 16;
    return v.f;
}
__device__ __forceinline__ unsigned short f2bf(float f) {
    unsigned int u = __float_as_uint(f);
    unsigned int r = (u + 0x7fffu + ((u >> 16) & 1u)) >> 16;   // RNE
    return (unsigned short)r;
}

// ---------------- degree / CSR build ----------------

__global__ void count_kernel(const int* __restrict__ dst, int* __restrict__ cnt) {
    int e = blockIdx.x * blockDim.x + threadIdx.x;
    if (e < E_EDGES) atomicAdd(&cnt[dst[e]], 1);
}

__global__ void dinv_kernel(const int* __restrict__ cnt, float* __restrict__ dinv) {
    int i = blockIdx.x * blockDim.x + threadIdx.x;
    if (i < N_NODES) dinv[i] = rsqrtf((float)cnt[i] + 1.0f);
}

__global__ void scan_kernel(const int* __restrict__ cnt, int* __restrict__ rowptr) {
    __shared__ int sums[256];
    const int t = threadIdx.x;
    const int CH = (N_NODES + 255) / 256;   // 79
    int begin = t * CH;
    int end = begin + CH; if (end > N_NODES) end = N_NODES;
    int s = 0;
    for (int i = begin; i < end; ++i) s += cnt[i];
    sums[t] = s;
    __syncthreads();
    if (t == 0) {
        int run = 0;
        for (int i = 0; i < 256; ++i) { int v = sums[i]; sums[i] = run; run += v; }
    }
    __syncthreads();
    int run = sums[t];
    for (int i = begin; i < end; ++i) { rowptr[i] = run; run += cnt[i]; }
    if (t == 0) rowptr[N_NODES] = E_EDGES;
}

__global__ void fill_kernel(const int* __restrict__ src, const int* __restrict__ dst,
                            const int* __restrict__ rowptr, int* __restrict__ cursor,
                            const float* __restrict__ dinv,
                            int* __restrict__ esrc, float* __restrict__ ecoef) {
    int e = blockIdx.x * blockDim.x + threadIdx.x;
    if (e < E_EDGES) {
        int s = src[e];
        int d = dst[e];
        int pos = atomicAdd(&cursor[d], 1);
        int idx = rowptr[d] + pos;
        esrc[idx] = s;
        ecoef[idx] = dinv[s] * dinv[d];
    }
}

// ---------------- weight prep: transpose + cast to bf16 ----------------

// w1t[n][k] = bf16(W1[k][n]);  n<256, k<512
__global__ void w1t_kernel(const float* __restrict__ W1, unsigned short* __restrict__ w1t) {
    int idx = blockIdx.x * blockDim.x + threadIdx.x;   // 131072 total
    int n = idx >> 9, k = idx & 511;
    w1t[idx] = f2bf(W1[k * H_DIM + n]);
}

// w2t[n][k] = n<40 ? bf16(W2[k][n]) : 0;  n<64, k<256
__global__ void w2t_kernel(const float* __restrict__ W2, unsigned short* __restrict__ w2t) {
    int idx = blockIdx.x * blockDim.x + threadIdx.x;   // 16384 total
    int n = idx >> 8, k = idx & 255;
    w2t[idx] = (n < C_DIM) ? f2bf(W2[k * C_DIM + n]) : (unsigned short)0;
}

// ---------------- MFMA GEMM: C[M,ldc](bf16) = A[M,K] @ BT[n][k](bf16)^T ----------------
// Block = 256 threads = 4 waves. Tile 64(M) x 64(N), BK=32.
// Wave w computes rows [w*16, w*16+16) x 64 cols (4 MFMA n-tiles).
// LDS rows padded to 40 shorts (80 B): max 2-way bank aliasing (free per m136).

template <int KDIM, bool A_FP32>
__global__ __launch_bounds__(256) void gemm_bf16_kernel(const void* __restrict__ Av,
                                                        const unsigned short* __restrict__ BT,
                                                        unsigned short* __restrict__ Cb,
                                                        int M, int ldc) {
    __shared__ short As[64 * 40];
    __shared__ short Bs[64 * 40];
    const int tid = threadIdx.x;
    const int w = tid >> 6;
    const int lane = tid & 63;
    const int lq = lane >> 4;      // quad 0..3
    const int lm = lane & 15;
    const int row0 = blockIdx.y * 64;
    const int col0 = blockIdx.x * 64;
    const int sr = tid >> 2;       // staging row 0..63
    const int sc = (tid & 3) * 8;  // staging k-chunk (8 bf16 = 16 B)

    floatx4 acc[4];
#pragma unroll
    for (int t = 0; t < 4; ++t) acc[t] = (floatx4){0.f, 0.f, 0.f, 0.f};

    for (int k0 = 0; k0 < KDIM; k0 += 32) {
        // ---- stage A tile (64 rows x 32 k) ----
        {
            const int gr = row0 + sr;
            short8 av;
            if (A_FP32) {
                if (gr < M) {
                    const float* p = (const float*)Av + (size_t)gr * KDIM + k0 + sc;
                    float4 a0 = *(const float4*)p;
                    float4 a1 = *(const float4*)(p + 4);
                    av[0] = (short)f2bf(a0.x); av[1] = (short)f2bf(a0.y);
                    av[2] = (short)f2bf(a0.z); av[3] = (short)f2bf(a0.w);
                    av[4] = (short)f2bf(a1.x); av[5] = (short)f2bf(a1.y);
                    av[6] = (short)f2bf(a1.z); av[7] = (short)f2bf(a1.w);
                } else {
                    av = (short8){0,0,0,0,0,0,0,0};
                }
            } else {
                if (gr < M) {
                    av = *(const short8*)((const unsigned short*)Av + (size_t)gr * KDIM + k0 + sc);
                } else {
                    av = (short8){0,0,0,0,0,0,0,0};
                }
            }
            *(short8*)&As[sr * 40 + sc] = av;
            // ---- stage B tile (64 n-rows x 32 k) ----
            *(short8*)&Bs[sr * 40 + sc] =
                *(const short8*)&BT[(size_t)(col0 + sr) * KDIM + k0 + sc];
        }
        __syncthreads();
        // ---- fragments + MFMA ----
        short8 af = *(const short8*)&As[(w * 16 + lm) * 40 + lq * 8];
#pragma unroll
        for (int t = 0; t < 4; ++t) {
            short8 bf = *(const short8*)&Bs[(t * 16 + lm) * 40 + lq * 8];
            acc[t] = __builtin_amdgcn_mfma_f32_16x16x32_bf16(af, bf, acc[t], 0, 0, 0);
        }
        __syncthreads();
    }
    // ---- store: C/D layout col=lane&15, row=quad*4+reg ----
#pragma unroll
    for (int t = 0; t < 4; ++t) {
#pragma unroll
        for (int r = 0; r < 4; ++r) {
            int row = row0 + w * 16 + lq * 4 + r;
            int col = col0 + t * 16 + lm;
            if (row < M) Cb[(size_t)row * ldc + col] = f2bf(acc[t][r]);
        }
    }
}

// ---------------- agg1: wave/node, gather bf16 rows, +b1, relu -> hrb bf16 ----------------

__global__ __launch_bounds__(256) void agg1_kernel(const unsigned short* __restrict__ h1b,
                                                   const int* __restrict__ rowptr,
                                                   const int* __restrict__ esrc,
                                                   const float* __restrict__ ecoef,
                                                   const float* __restrict__ dinv,
                                                   const float* __restrict__ b1,
                                                   unsigned short* __restrict__ hrb) {
    const int i = (blockIdx.x * 256 + threadIdx.x) >> 6;   // node
    const int lane = threadIdx.x & 63;
    const int f0 = lane * 4;                               // 4 bf16 features per lane
    const float di = dinv[i];
    const int rb = rowptr[i], re = rowptr[i + 1];
    ushort4 sv = *(const ushort4*)&h1b[(size_t)i * H_DIM + f0];
    const float ws = di * di;
    float ax = ws * bf2f(sv.x), ay = ws * bf2f(sv.y);
    float az = ws * bf2f(sv.z), aw = ws * bf2f(sv.w);
    int k = rb;
    for (; k + 1 < re; k += 2) {
        int s0 = esrc[k], s1 = esrc[k + 1];
        float w0 = ecoef[k], w1 = ecoef[k + 1];
        ushort4 v0 = *(const ushort4*)&h1b[(size_t)s0 * H_DIM + f0];
        ushort4 v1 = *(const ushort4*)&h1b[(size_t)s1 * H_DIM + f0];
        ax = fmaf(w0, bf2f(v0.x), ax); ay = fmaf(w0, bf2f(v0.y), ay);
        az = fmaf(w0, bf2f(v0.z), az); aw = fmaf(w0, bf2f(v0.w), aw);
        ax = fmaf(w1, bf2f(v1.x), ax); ay = fmaf(w1, bf2f(v1.y), ay);
        az = fmaf(w1, bf2f(v1.z), az); aw = fmaf(w1, bf2f(v1.w), aw);
    }
    if (k < re) {
        int s0 = esrc[k];
        float w0 = ecoef[k];
        ushort4 v0 = *(const ushort4*)&h1b[(size_t)s0 * H_DIM + f0];
        ax = fmaf(w0, bf2f(v0.x), ax); ay = fmaf(w0, bf2f(v0.y), ay);
        az = fmaf(w0, bf2f(v0.z), az); aw = fmaf(w0, bf2f(v0.w), aw);
    }
    float4 bb = *(const float4*)&b1[f0];
    ax = fmaxf(ax + bb.x, 0.f); ay = fmaxf(ay + bb.y, 0.f);
    az = fmaxf(az + bb.z, 0.f); aw = fmaxf(aw + bb.w, 0.f);
    ushort4 o = make_ushort4(f2bf(ax), f2bf(ay), f2bf(az), f2bf(aw));
    *(ushort4*)&hrb[(size_t)i * H_DIM + f0] = o;
}

// ---------------- agg2: wave/node, gather h2b (64-pad bf16), +b2 -> out fp32 ----------------

__global__ __launch_bounds__(256) void agg2_kernel(const unsigned short* __restrict__ h2b,
                                                   const int* __restrict__ rowptr,
                                                   const int* __restrict__ esrc,
                                                   const float* __restrict__ ecoef,
                                                   const float* __restrict__ dinv,
                                                   const float* __restrict__ b2,
                                                   float* __restrict__ out) {
    const int i = (blockIdx.x * 256 + threadIdx.x) >> 6;   // node
    const int lane = threadIdx.x & 63;
    if (lane >= 20) return;                                 // 20 lanes x 2 cols = 40
    const int c0 = lane * 2;
    const float di = dinv[i];
    const int rb = rowptr[i], re = rowptr[i + 1];
    unsigned int sv = *(const unsigned int*)&h2b[(size_t)i * C_PAD + c0];
    const float ws = di * di;
    float a0 = ws * bf2f((unsigned short)(sv & 0xffff));
    float a1 = ws * bf2f((unsigned short)(sv >> 16));
    for (int k = rb; k < re; ++k) {
        int s = esrc[k];
        float w = ecoef[k];
        unsigned int v = *(const unsigned int*)&h2b[(size_t)s * C_PAD + c0];
        a0 = fmaf(w, bf2f((unsigned short)(v & 0xffff)), a0);
        a1 = fmaf(w, bf2f((unsigned short)(v >> 16)), a1);
    }
    float2 bb = *(const float2*)&b2[c0];
    float2 o = make_float2(a0 + bb.x, a1 + bb.y);
    *(float2*)&out[(size_t)i * C_DIM + c0] = o;
}

// ---------------- launch ----------------

extern "C" void kernel_launch(void* const* d_in, const int* in_sizes, int n_in,
                              void* d_out, int out_size, void* d_ws, size_t ws_size,
                              hipStream_t stream) {
    const float* x   = (const float*)d_in[0];
    const int*   ei  = (const int*)d_in[1];
    const float* W1  = (const float*)d_in[2];
    const float* b1  = (const float*)d_in[3];
    const float* W2  = (const float*)d_in[4];
    const float* b2  = (const float*)d_in[5];
    float* out = (float*)d_out;

    const int* src = ei;            // edge_index[0]
    const int* dst = ei + E_EDGES;  // edge_index[1]

    // workspace layout (16B-aligned; h2b 128B-aligned). Total ~28.8 MB.
    char* ws = (char*)d_ws;
    int*            cnt    = (int*)(ws + 0);             //    80000 B
    float*          dinv   = (float*)(ws + 80000);       //    80000 B
    int*            rowptr = (int*)(ws + 160000);        //    80016 B
    int*            cursor = (int*)(ws + 240016);        //    80000 B
    int*            esrc   = (int*)(ws + 320016);        //  2560000 B
    float*          ecoef  = (float*)(ws + 2880016);     //  2560000 B
    unsigned short* w1t    = (unsigned short*)(ws + 5440016);   //   262144 B
    unsigned short* w2t    = (unsigned short*)(ws + 5702160);   //    32768 B
    unsigned short* h1b    = (unsigned short*)(ws + 5734928);   // 10240000 B
    unsigned short* hrb    = (unsigned short*)(ws + 15974928);  // 10240000 B
    unsigned short* h2b    = (unsigned short*)(ws + 26215040);  //  2560000 B (128B-aligned)

    hipMemsetAsync(cnt, 0, N_NODES * sizeof(int), stream);
    hipMemsetAsync(cursor, 0, N_NODES * sizeof(int), stream);

    count_kernel<<<(E_EDGES + 255) / 256, 256, 0, stream>>>(dst, cnt);
    dinv_kernel<<<(N_NODES + 255) / 256, 256, 0, stream>>>(cnt, dinv);
    scan_kernel<<<1, 256, 0, stream>>>(cnt, rowptr);
    fill_kernel<<<(E_EDGES + 255) / 256, 256, 0, stream>>>(src, dst, rowptr, cursor, dinv,
                                                           esrc, ecoef);

    w1t_kernel<<<(F_IN * H_DIM) / 256, 256, 0, stream>>>(W1, w1t);
    w2t_kernel<<<(H_DIM * C_PAD) / 256, 256, 0, stream>>>(W2, w2t);

    dim3 g1(H_DIM / 64, (N_NODES + 63) / 64);   // 4 x 313
    gemm_bf16_kernel<F_IN, true><<<g1, 256, 0, stream>>>(x, w1t, h1b, N_NODES, H_DIM);

    agg1_kernel<<<N_NODES / 4, 256, 0, stream>>>(h1b, rowptr, esrc, ecoef, dinv, b1, hrb);

    dim3 g2(1, (N_NODES + 63) / 64);            // 1 x 313
    gemm_bf16_kernel<H_DIM, false><<<g2, 256, 0, stream>>>(hrb, w2t, h2b, N_NODES, C_PAD);

    agg2_kernel<<<N_NODES / 4, 256, 0, stream>>>(h2b, rowptr, esrc, ecoef, dinv, b2, out);
}